// Round 6
// baseline (348.831 us; speedup 1.0000x reference)
//
#include <hip/hip_runtime.h>
#include <hip/hip_bf16.h>

#define K3   40
#define CO   64
#define GM   16      // m per group (= MFMA tile rows)
#define CHK  10      // k-slots per staged chunk (4 chunks per group)
#define FS   200     // shorts per ycat row in LDS (192 data + 8 pad)
#define BN_EPS 1e-5f

typedef __attribute__((ext_vector_type(8))) short short8;
typedef __attribute__((ext_vector_type(4))) float f32x4;

union U8 { short8 s; uint4 u; };

static __device__ __forceinline__ short f2bf(float f) {
  union { __hip_bfloat16 b; short s; } u; u.b = __float2bfloat16(f); return u.s;
}
static __device__ __forceinline__ unsigned pk2(float a, float b) {
  union { __hip_bfloat16 b; unsigned short s; } ua, ub;
  ua.b = __float2bfloat16(a); ub.b = __float2bfloat16(b);
  return (unsigned)ua.s | ((unsigned)ub.s << 16);
}
static __device__ __forceinline__ void gload_lds16(const void* g, void* l) {
  __builtin_amdgcn_global_load_lds(
      (const __attribute__((address_space(1))) unsigned int*)g,
      (__attribute__((address_space(3))) unsigned int*)l, 16, 0, 0);
}

// ---------------------------------------------------------------------------
// Output buffer is FLOAT32. Layout: n_p[M*3] | y[M*64] | n_o[1].
// xb (bf16 copy of x) lives in the out_y region during k_pre..k_branch;
// k_fuse overwrites it with z afterwards (stream-ordered).
// Workspace: hmax1|hmax2|hmax3 (3*M*64 f32) | stats(512 f32)
// ---------------------------------------------------------------------------

// k_pre: x -> bf16 table | n_p centroid table | stats zero | n_o.
__global__ void k_pre(const float* __restrict__ x, const float* __restrict__ p,
                      const int* __restrict__ fps,
                      short* __restrict__ xb, float* __restrict__ out_np,
                      float* __restrict__ stats, float* __restrict__ out_no,
                      int N, int M)
{
  int t = blockIdx.x * blockDim.x + threadIdx.x;
  int nxb = N * 4;                       // N*32 elems / 8 per thread
  if (t < nxb) {
    const float4* src = (const float4*)x + (size_t)t * 2;
    float4 f0 = src[0], f1 = src[1];
    uint4 o = make_uint4(pk2(f0.x, f0.y), pk2(f0.z, f0.w),
                         pk2(f1.x, f1.y), pk2(f1.z, f1.w));
    ((uint4*)xb)[t] = o;
    return;
  }
  int t2 = t - nxb;
  if (t2 < M) {
    int fi = fps[t2];
    out_np[(size_t)t2 * 3 + 0] = p[(size_t)fi * 3 + 0];
    out_np[(size_t)t2 * 3 + 1] = p[(size_t)fi * 3 + 1];
    out_np[(size_t)t2 * 3 + 2] = p[(size_t)fi * 3 + 2];
    return;
  }
  int t3 = t2 - M;
  if (t3 < 512) {
    stats[t3] = 0.f;
    if (t3 == 0) out_no[0] = (float)M;
  }
}

// ---------------------------------------------------------------------------
// k_branch: one 16-m group per block; K in 4 chunks of 10 (aligned to the
// branch boundaries). 14 KB LDS -> 8 blocks/CU (wave-slot max); inter-block
// TLP is the latency-hiding mechanism. Per chunk: 3 gload_lds16 per wave
// (addresses from LDS-staged knn) + rel computed from L2-resident p by 160
// threads; one barrier; 10 MFMA k-steps. hmax via LDS bounce -> full lines.
// ---------------------------------------------------------------------------
__global__ void __launch_bounds__(256, 8) k_branch(
    const float* __restrict__ p, const short* __restrict__ xb,
    const float* __restrict__ np, const int* __restrict__ knn,
    const float* __restrict__ w1, const float* __restrict__ w2,
    const float* __restrict__ w3,
    float* __restrict__ hmax1, float* __restrict__ hmax2,
    float* __restrict__ hmax3,
    float* __restrict__ stats, int M)
{
  __shared__ __align__(16) char smem[14336];
  short* abuf  = (short*)smem;              // 10240 B, row = kl*16+ml (64B rows)
  uint2* rbuf  = (uint2*)(smem + 10240);    //  1280 B
  int*   knn_s = (int*)(smem + 11520);      //  2560 B (ml*40 + k)

  const int tid  = threadIdx.x;
  const int wv   = tid >> 6;
  const int lane = tid & 63;
  const int q    = lane >> 4;    // quad
  const int nn   = lane & 15;    // A-row (m_local) and B-col within tile
  const int cg   = wv * 16 + nn; // this lane's output channel
  const int base = blockIdx.x * GM;

  // B fragments: lane holds w[k][cg] permuted to feat d-order:
  // d<32 -> w row 3+d (x part); d in [32,35) -> w row d-32 (rel); else 0.
  short8 bw1[2], bw2[2], bw3[2];
#pragma unroll
  for (int s = 0; s < 2; ++s) {
#pragma unroll
    for (int j = 0; j < 8; ++j) {
      int d = s * 32 + q * 8 + j;
      int row = (d < 32) ? (3 + d) : ((d < 35) ? (d - 32) : -1);
      bw1[s][j] = f2bf(row >= 0 ? w1[row * CO + cg] : 0.f);
      bw2[s][j] = f2bf(row >= 0 ? w2[row * CO + cg] : 0.f);
      bw3[s][j] = f2bf(row >= 0 ? w3[row * CO + cg] : 0.f);
    }
  }

  // stage knn for the group once (contiguous 2560 B, int4-coalesced)
  if (tid < 160)
    ((int4*)knn_s)[tid] = ((const int4*)(knn + (size_t)base * K3))[tid];
  __syncthreads();

  float s1b0 = 0.f, s1b1 = 0.f, s1b2 = 0.f;
  float s2b0 = 0.f, s2b1 = 0.f, s2b2 = 0.f;
  const f32x4 zz = {0.f, 0.f, 0.f, 0.f};

  // wave wv stages rows [wv*40, wv*40+40): 3 gloads (last half-masked).
  // rel rows by tid<160 (row rr = tid: kl = tid>>4, ml = tid&15).
#define STAGE(ch) {                                                           \
    _Pragma("unroll")                                                         \
    for (int j = 0; j < 3; ++j) {                                             \
      if (j < 2 || lane < 32) {                                               \
        int r  = wv * 40 + j * 16 + (lane >> 2);                              \
        int gi = knn_s[(r & 15) * K3 + (ch) * CHK + (r >> 4)];                \
        gload_lds16(xb + (size_t)gi * 32 + (lane & 3) * 8,                    \
                    &abuf[(wv * 40 + j * 16) * 32]);                          \
      }                                                                       \
    }                                                                         \
    if (tid < CHK * GM) {                                                     \
      int ml = tid & 15, kl = tid >> 4;                                       \
      int gi = knn_s[ml * K3 + (ch) * CHK + kl];                              \
      const float* pg  = p  + (size_t)gi * 3;                                 \
      const float* npp = np + (size_t)(base + ml) * 3;                        \
      float rx = pg[0] - npp[0];                                              \
      float ry = pg[1] - npp[1];                                              \
      float rz = pg[2] - npp[2];                                              \
      rbuf[tid] = make_uint2(pk2(rx, ry), pk2(rz, 0.f));                      \
    }                                                                         \
  }

#define LOADA(kl)                                                             \
    const short8 a0 = *(const short8*)&abuf[((kl) * GM + nn) * 32 + q * 8];   \
    const uint2 rv = rbuf[(kl) * GM + nn];                                    \
    U8 t1_; t1_.u = make_uint4(rv.x, rv.y, 0u, 0u);                           \
    const short8 a1 = t1_.s;

#define STAT(h, mx, s1, s2)                                                   \
    _Pragma("unroll")                                                         \
    for (int r = 0; r < 4; ++r) {                                             \
      float hv = (h)[r];                                                      \
      (mx)[r] = fmaxf((mx)[r], hv);                                           \
      (s1) += hv;                                                             \
      (s2) = fmaf(hv, hv, (s2));                                              \
    }

  float mx1[4], mx2[4], mx3[4];
#pragma unroll
  for (int r = 0; r < 4; ++r) { mx1[r] = -3.4e38f; mx2[r] = -3.4e38f; mx3[r] = -3.4e38f; }

  // ---- chunk 0: kg in [0,10), branches 1,2,3 ----
  STAGE(0)
  __syncthreads();
#pragma unroll 2
  for (int kl = 0; kl < 10; ++kl) {
    LOADA(kl)
    f32x4 h3 = __builtin_amdgcn_mfma_f32_16x16x32_bf16(a0, bw3[0], zz, 0, 0, 0);
    h3 = __builtin_amdgcn_mfma_f32_16x16x32_bf16(a1, bw3[1], h3, 0, 0, 0);
    f32x4 h2 = __builtin_amdgcn_mfma_f32_16x16x32_bf16(a0, bw2[0], zz, 0, 0, 0);
    h2 = __builtin_amdgcn_mfma_f32_16x16x32_bf16(a1, bw2[1], h2, 0, 0, 0);
    f32x4 h1 = __builtin_amdgcn_mfma_f32_16x16x32_bf16(a0, bw1[0], zz, 0, 0, 0);
    h1 = __builtin_amdgcn_mfma_f32_16x16x32_bf16(a1, bw1[1], h1, 0, 0, 0);
    STAT(h3, mx3, s1b2, s2b2)
    STAT(h2, mx2, s1b1, s2b1)
    STAT(h1, mx1, s1b0, s2b0)
  }

  // ---- chunk 1: kg in [10,20), branches 2,3 ----
  __syncthreads();
  STAGE(1)
  __syncthreads();
#pragma unroll 2
  for (int kl = 0; kl < 10; ++kl) {
    LOADA(kl)
    f32x4 h3 = __builtin_amdgcn_mfma_f32_16x16x32_bf16(a0, bw3[0], zz, 0, 0, 0);
    h3 = __builtin_amdgcn_mfma_f32_16x16x32_bf16(a1, bw3[1], h3, 0, 0, 0);
    f32x4 h2 = __builtin_amdgcn_mfma_f32_16x16x32_bf16(a0, bw2[0], zz, 0, 0, 0);
    h2 = __builtin_amdgcn_mfma_f32_16x16x32_bf16(a1, bw2[1], h2, 0, 0, 0);
    STAT(h3, mx3, s1b2, s2b2)
    STAT(h2, mx2, s1b1, s2b1)
  }

  // ---- chunks 2,3: kg in [20,40), branch 3 only ----
#pragma unroll 1
  for (int ch = 2; ch < 4; ++ch) {
    __syncthreads();
    STAGE(ch)
    __syncthreads();
#pragma unroll 2
    for (int kl = 0; kl < 10; ++kl) {
      LOADA(kl)
      f32x4 h3 = __builtin_amdgcn_mfma_f32_16x16x32_bf16(a0, bw3[0], zz, 0, 0, 0);
      h3 = __builtin_amdgcn_mfma_f32_16x16x32_bf16(a1, bw3[1], h3, 0, 0, 0);
      STAT(h3, mx3, s1b2, s2b2)
    }
  }

  // ---- hmax via LDS bounce -> full-line coalesced writes ----
  __syncthreads();                       // all LDS reads done
  float* hb_s = (float*)smem;            // 12288 B of 14336 B
#pragma unroll
  for (int r = 0; r < 4; ++r) {
    int ml = q * 4 + r;
    hb_s[0 * 1024 + ml * 64 + cg] = mx1[r];
    hb_s[1 * 1024 + ml * 64 + cg] = mx2[r];
    hb_s[2 * 1024 + ml * 64 + cg] = mx3[r];
  }
  __syncthreads();
  {
    const float4* s4 = (const float4*)hb_s;
    ((float4*)(hmax1 + (size_t)base * CO))[tid] = s4[tid];
    ((float4*)(hmax2 + (size_t)base * CO))[tid] = s4[256 + tid];
    ((float4*)(hmax3 + (size_t)base * CO))[tid] = s4[512 + tid];
  }
#undef STAGE
#undef LOADA
#undef STAT

  // ---- stats: reduce across quads (same c), then one atomic per (c,stat) ----
  {
    float v;
    v = s1b0; v += __shfl_xor(v, 16); v += __shfl_xor(v, 32);
    if (q == 0) atomicAdd(&stats[0 * 64 + cg], v);
    v = s1b1; v += __shfl_xor(v, 16); v += __shfl_xor(v, 32);
    if (q == 0) atomicAdd(&stats[1 * 64 + cg], v);
    v = s1b2; v += __shfl_xor(v, 16); v += __shfl_xor(v, 32);
    if (q == 0) atomicAdd(&stats[2 * 64 + cg], v);
    v = s2b0; v += __shfl_xor(v, 16); v += __shfl_xor(v, 32);
    if (q == 0) atomicAdd(&stats[192 + 0 * 64 + cg], v);
    v = s2b1; v += __shfl_xor(v, 16); v += __shfl_xor(v, 32);
    if (q == 0) atomicAdd(&stats[192 + 1 * 64 + cg], v);
    v = s2b2; v += __shfl_xor(v, 16); v += __shfl_xor(v, 32);
    if (q == 0) atomicAdd(&stats[192 + 2 * 64 + cg], v);
  }
}

// ---------------------------------------------------------------------------
// k_fuse (proven form): BN affines in preamble; ycat staged bf16 in LDS;
// z = ycat@w + b via 6 accumulating MFMAs; z stats.
// ---------------------------------------------------------------------------
__global__ void __launch_bounds__(256) k_fuse(
    const float* __restrict__ hmax1, const float* __restrict__ hmax2,
    const float* __restrict__ hmax3,
    const float* __restrict__ w, const float* __restrict__ bias,
    const float* __restrict__ g1, const float* __restrict__ g2,
    const float* __restrict__ g3,
    const float* __restrict__ be1, const float* __restrict__ be2,
    const float* __restrict__ be3,
    float* __restrict__ zout, float* __restrict__ stats, int M)
{
  __shared__ __align__(16) short ybuf[GM * FS];   // 6400 B
  __shared__ float sc_s[192], sh_s[192];

  const int tid  = threadIdx.x;
  const int wv   = tid >> 6;
  const int lane = tid & 63;
  const int q    = lane >> 4;
  const int nn   = lane & 15;
  const int cg   = wv * 16 + nn;

  if (tid < 192) {
    int b = tid >> 6, c = tid & 63;
    float cnt = (float)M * (float)(10 << b);
    float mu  = stats[tid] / cnt;
    float var = stats[192 + tid] / cnt - mu * mu;
    const float* g  = (b == 0) ? g1 : ((b == 1) ? g2 : g3);
    const float* be = (b == 0) ? be1 : ((b == 1) ? be2 : be3);
    float sc = g[c] * rsqrtf(var + BN_EPS);
    sc_s[tid] = sc;
    sh_s[tid] = be[c] - mu * sc;
  }

  short8 bw[6];
#pragma unroll
  for (int s = 0; s < 6; ++s)
#pragma unroll
    for (int j = 0; j < 8; ++j)
      bw[s][j] = f2bf(w[(s * 32 + q * 8 + j) * CO + cg]);

  const float bia = bias[cg];
  float s1 = 0.f, s2 = 0.f;

  const int ml_s = tid >> 4;          // staging: m_local 0..15
  const int c4   = (tid & 15) * 4;    // staging: 4 channels
  __syncthreads();                    // sc_s/sh_s ready

  const int ngrp = M / GM;
  for (int grp = blockIdx.x; grp < ngrp; grp += gridDim.x) {
    const int base = grp * GM;
    // ---- stage ycat (affine + relu + bf16) ----
#pragma unroll
    for (int b = 0; b < 3; ++b) {
      const float* hb = (b == 0) ? hmax1 : ((b == 1) ? hmax2 : hmax3);
      float4 v  = *(const float4*)&hb[(size_t)(base + ml_s) * CO + c4];
      float4 sc = *(const float4*)&sc_s[b * 64 + c4];
      float4 sh = *(const float4*)&sh_s[b * 64 + c4];
      float y0 = fmaxf(fmaf(v.x, sc.x, sh.x), 0.f);
      float y1 = fmaxf(fmaf(v.y, sc.y, sh.y), 0.f);
      float y2 = fmaxf(fmaf(v.z, sc.z, sh.z), 0.f);
      float y3 = fmaxf(fmaf(v.w, sc.w, sh.w), 0.f);
      *(uint2*)&ybuf[ml_s * FS + b * 64 + c4] = make_uint2(pk2(y0, y1), pk2(y2, y3));
    }
    __syncthreads();
    // ---- 6 accumulating MFMAs ----
    const short* ar = &ybuf[nn * FS + q * 8];
    f32x4 acc = {0.f, 0.f, 0.f, 0.f};
#pragma unroll
    for (int s = 0; s < 6; ++s) {
      short8 a = *(const short8*)(ar + s * 32);
      acc = __builtin_amdgcn_mfma_f32_16x16x32_bf16(a, bw[s], acc, 0, 0, 0);
    }
#pragma unroll
    for (int r = 0; r < 4; ++r) {
      float z = acc[r] + bia;
      int m = base + q * 4 + r;
      zout[(size_t)m * CO + cg] = z;
      s1 += z; s2 = fmaf(z, z, s2);
    }
    __syncthreads();   // ybuf reuse
  }

  float v;
  v = s1; v += __shfl_xor(v, 16); v += __shfl_xor(v, 32);
  if (q == 0) atomicAdd(&stats[384 + cg], v);
  v = s2; v += __shfl_xor(v, 16); v += __shfl_xor(v, 32);
  if (q == 0) atomicAdd(&stats[448 + cg], v);
}

// ---------------------------------------------------------------------------
// k_out: final BN params inline; y = relu(BN(z)) in place, float4; n_o.
// ---------------------------------------------------------------------------
__global__ void k_out(float* __restrict__ y, const float* __restrict__ stats,
                      const float* __restrict__ g, const float* __restrict__ be,
                      float* __restrict__ out_no, int M)
{
  int t = blockIdx.x * blockDim.x + threadIdx.x;
  int total = M * 16;                 // in float4 units (M*64 floats)
  if (t < total) {
    int c0 = (t & 15) * 4;
    float rm = 1.f / (float)M;
    float4 v  = ((const float4*)y)[t];
    float4 sA = *(const float4*)&stats[384 + c0];
    float4 sB = *(const float4*)&stats[448 + c0];
    float4 gv = *(const float4*)&g[c0];
    float4 bv = *(const float4*)&be[c0];
    float mu0 = sA.x * rm, mu1 = sA.y * rm, mu2 = sA.z * rm, mu3 = sA.w * rm;
    float sc0 = gv.x * rsqrtf(sB.x * rm - mu0 * mu0 + BN_EPS);
    float sc1 = gv.y * rsqrtf(sB.y * rm - mu1 * mu1 + BN_EPS);
    float sc2 = gv.z * rsqrtf(sB.z * rm - mu2 * mu2 + BN_EPS);
    float sc3 = gv.w * rsqrtf(sB.w * rm - mu3 * mu3 + BN_EPS);
    float4 o;
    o.x = fmaxf(fmaf(v.x, sc0, bv.x - mu0 * sc0), 0.f);
    o.y = fmaxf(fmaf(v.y, sc1, bv.y - mu1 * sc1), 0.f);
    o.z = fmaxf(fmaf(v.z, sc2, bv.z - mu2 * sc2), 0.f);
    o.w = fmaxf(fmaf(v.w, sc3, bv.w - mu3 * sc3), 0.f);
    ((float4*)y)[t] = o;
  }
  if (t == 0) out_no[0] = (float)M;
}

extern "C" void kernel_launch(void* const* d_in, const int* in_sizes, int n_in,
                              void* d_out, int out_size, void* d_ws, size_t ws_size,
                              hipStream_t stream) {
  const float* p   = (const float*)d_in[0];
  const float* x   = (const float*)d_in[1];
  const int*   fps = (const int*)d_in[3];
  const int*   knn = (const int*)d_in[4];
  const float* w1  = (const float*)d_in[5];
  const float* w2  = (const float*)d_in[6];
  const float* w3  = (const float*)d_in[7];
  const float* w   = (const float*)d_in[8];
  const float* b   = (const float*)d_in[9];
  const float* g1  = (const float*)d_in[10];
  const float* g2  = (const float*)d_in[11];
  const float* g3  = (const float*)d_in[12];
  const float* g   = (const float*)d_in[13];
  const float* be1 = (const float*)d_in[14];
  const float* be2 = (const float*)d_in[15];
  const float* be3 = (const float*)d_in[16];
  const float* be  = (const float*)d_in[17];

  const int M = in_sizes[3];
  const int N = in_sizes[1] / 32;   // x is [N, 32]

  float* ws    = (float*)d_ws;
  float* hmax1 = ws;
  float* hmax2 = hmax1 + (size_t)M * 64;
  float* hmax3 = hmax2 + (size_t)M * 64;
  float* stats = hmax3 + (size_t)M * 64;   // 512 floats

  float* out    = (float*)d_out;
  float* out_np = out;                       // [0, 3M)
  float* out_y  = out + (size_t)3 * M;       // [3M, 67M)
  float* out_no = out + (size_t)67 * M;      // [67M]
  short* xb     = (short*)out_y;             // bf16 x table, dead before k_fuse

  int pre_threads = 4 * N + M + 512;
  k_pre<<<(pre_threads + 255) / 256, 256, 0, stream>>>(x, p, fps, xb, out_np,
                                                       stats, out_no, N, M);
  k_branch<<<M / GM, 256, 0, stream>>>(p, xb, out_np, knn, w1, w2, w3,
                                       hmax1, hmax2, hmax3, stats, M);
  k_fuse<<<2048, 256, 0, stream>>>(hmax1, hmax2, hmax3, w, b,
                                   g1, g2, g3, be1, be2, be3,
                                   out_y, stats, M);
  k_out<<<(M * 16 + 255) / 256, 256, 0, stream>>>(out_y, stats, g, be, out_no, M);
}

// Round 7
// 316.482 us; speedup vs baseline: 1.1022x; 1.1022x over previous
//
#include <hip/hip_runtime.h>
#include <hip/hip_bf16.h>

#define K3   40
#define CO   64
#define GM   16      // m per group (= MFMA tile rows)
#define CHK  20      // k-slots per staged half (2 halves per group)
#define FS   200     // shorts per ycat row in LDS (192 data + 8 pad)
#define BN_EPS 1e-5f

typedef __attribute__((ext_vector_type(8))) short short8;
typedef __attribute__((ext_vector_type(4))) float f32x4;

union U8 { short8 s; uint4 u; };

static __device__ __forceinline__ short f2bf(float f) {
  union { __hip_bfloat16 b; short s; } u; u.b = __float2bfloat16(f); return u.s;
}
static __device__ __forceinline__ unsigned pk2(float a, float b) {
  union { __hip_bfloat16 b; unsigned short s; } ua, ub;
  ua.b = __float2bfloat16(a); ub.b = __float2bfloat16(b);
  return (unsigned)ua.s | ((unsigned)ub.s << 16);
}
static __device__ __forceinline__ void gload_lds16(const void* g, void* l) {
  __builtin_amdgcn_global_load_lds(
      (const __attribute__((address_space(1))) unsigned int*)g,
      (__attribute__((address_space(3))) unsigned int*)l, 16, 0, 0);
}

// ---------------------------------------------------------------------------
// Output buffer is FLOAT32. Layout: n_p[M*3] | y[M*64] | n_o[1].
// xb (bf16 copy of x) lives in the out_y region during k_pre..k_branch;
// k_fuse overwrites it with z afterwards (stream-ordered).
// Workspace: hmax1|hmax2|hmax3 (3*M*64 f32) | stats(512 f32)
// ---------------------------------------------------------------------------

// k_pre: x -> bf16 table | n_p centroid table | stats zero | n_o.
__global__ void k_pre(const float* __restrict__ x, const float* __restrict__ p,
                      const int* __restrict__ fps,
                      short* __restrict__ xb, float* __restrict__ out_np,
                      float* __restrict__ stats, float* __restrict__ out_no,
                      int N, int M)
{
  int t = blockIdx.x * blockDim.x + threadIdx.x;
  int nxb = N * 4;                       // N*32 elems / 8 per thread
  if (t < nxb) {
    const float4* src = (const float4*)x + (size_t)t * 2;
    float4 f0 = src[0], f1 = src[1];
    uint4 o = make_uint4(pk2(f0.x, f0.y), pk2(f0.z, f0.w),
                         pk2(f1.x, f1.y), pk2(f1.z, f1.w));
    ((uint4*)xb)[t] = o;
    return;
  }
  int t2 = t - nxb;
  if (t2 < M) {
    int fi = fps[t2];
    out_np[(size_t)t2 * 3 + 0] = p[(size_t)fi * 3 + 0];
    out_np[(size_t)t2 * 3 + 1] = p[(size_t)fi * 3 + 1];
    out_np[(size_t)t2 * 3 + 2] = p[(size_t)fi * 3 + 2];
    return;
  }
  int t3 = t2 - M;
  if (t3 < 512) {
    stats[t3] = 0.f;
    if (t3 == 0) out_no[0] = (float)M;
  }
}

// ---------------------------------------------------------------------------
// k_branch: 2 groups per block (grid M/32), 4 pipelined halves of 20 k-slots.
// Double-buffered LDS staging: stage half t+1 (5 gload_lds/thread + rel from
// L2-resident p) -> s_waitcnt vmcnt(5) keeps the new DMAs in flight across a
// raw s_barrier -> compute half t. 51.2 KB LDS -> 3 blocks/CU: the known
// minimum-traffic operating point, now with intra-block latency overlap.
// ---------------------------------------------------------------------------
__global__ void __launch_bounds__(256, 3) k_branch(
    const float* __restrict__ p, const short* __restrict__ xb,
    const float* __restrict__ np, const int* __restrict__ knn,
    const float* __restrict__ w1, const float* __restrict__ w2,
    const float* __restrict__ w3,
    float* __restrict__ hmax1, float* __restrict__ hmax2,
    float* __restrict__ hmax3,
    float* __restrict__ stats, int M)
{
  __shared__ __align__(16) short abuf[2][CHK * GM * 32];   // 2 x 20480 B
  __shared__ __align__(16) uint2 rbuf[2][CHK * GM];        // 2 x 2560 B
  __shared__ __align__(16) int   knn_s[2][GM * K3];        // 2 x 2560 B

  const int tid  = threadIdx.x;
  const int wv   = tid >> 6;
  const int lane = tid & 63;
  const int q    = lane >> 4;    // quad
  const int nn   = lane & 15;    // A-row (m_local) and B-col within tile
  const int cg   = wv * 16 + nn; // this lane's output channel
  const int sub8 = (lane & 3) * 8;   // 16B sub-chunk of a 64B row (in shorts)
  const int rml  = lane >> 2;        // m_local of the staged row
  const int base0 = blockIdx.x * GM;
  const int base1 = (blockIdx.x + gridDim.x) * GM;

  // B fragments: lane holds w[k][cg] permuted to feat d-order:
  // d<32 -> w row 3+d (x part); d in [32,35) -> w row d-32 (rel); else 0.
  short8 bw1[2], bw2[2], bw3[2];
#pragma unroll
  for (int s = 0; s < 2; ++s) {
#pragma unroll
    for (int j = 0; j < 8; ++j) {
      int d = s * 32 + q * 8 + j;
      int row = (d < 32) ? (3 + d) : ((d < 35) ? (d - 32) : -1);
      bw1[s][j] = f2bf(row >= 0 ? w1[row * CO + cg] : 0.f);
      bw2[s][j] = f2bf(row >= 0 ? w2[row * CO + cg] : 0.f);
      bw3[s][j] = f2bf(row >= 0 ? w3[row * CO + cg] : 0.f);
    }
  }

  // stage knn for BOTH groups once (contiguous, int4-coalesced)
  if (tid < 160) {
    ((int4*)knn_s[0])[tid] = ((const int4*)(knn + (size_t)base0 * K3))[tid];
    ((int4*)knn_s[1])[tid] = ((const int4*)(knn + (size_t)base1 * K3))[tid];
  }
  __syncthreads();

  float s1b0 = 0.f, s1b1 = 0.f, s1b2 = 0.f;
  float s2b0 = 0.f, s2b1 = 0.f, s2b2 = 0.f;
  const f32x4 zz = {0.f, 0.f, 0.f, 0.f};

  // rel rows (320 per half): thread tid does rr=tid, tid<64 also rr=256+tid.
  // np row reused (same ml for both). Consuming these loads also retires the
  // previous half's gload_lds (they are older in the vmcnt queue).
#define STAGE_REL(gI, half, b, baseV) {                                       \
    int ml_ = tid & 15;                                                       \
    const float* npp_ = np + (size_t)((baseV) + ml_) * 3;                     \
    float npx_ = npp_[0], npy_ = npp_[1], npz_ = npp_[2];                     \
    int kl0_ = tid >> 4;                                                      \
    int gi0_ = knn_s[gI][ml_ * K3 + (half) * CHK + kl0_];                     \
    const float* pg0_ = p + (size_t)gi0_ * 3;                                 \
    rbuf[b][kl0_ * GM + ml_] =                                                \
        make_uint2(pk2(pg0_[0] - npx_, pg0_[1] - npy_),                       \
                   pk2(pg0_[2] - npz_, 0.f));                                 \
    if (tid < 64) {                                                           \
      int kl1_ = 16 + (tid >> 4);                                             \
      int gi1_ = knn_s[gI][ml_ * K3 + (half) * CHK + kl1_];                   \
      const float* pg1_ = p + (size_t)gi1_ * 3;                               \
      rbuf[b][kl1_ * GM + ml_] =                                              \
          make_uint2(pk2(pg1_[0] - npx_, pg1_[1] - npy_),                     \
                     pk2(pg1_[2] - npz_, 0.f));                               \
    }                                                                         \
  }

  // 5 pure-DMA loads per thread; wave wv owns kl in [wv*5, wv*5+5)
#define STAGE_XB(gI, half, b) {                                               \
    _Pragma("unroll")                                                         \
    for (int j = 0; j < 5; ++j) {                                             \
      int kl_ = wv * 5 + j;                                                   \
      int gi_ = knn_s[gI][rml * K3 + (half) * CHK + kl_];                     \
      gload_lds16(xb + (size_t)gi_ * 32 + sub8,                               \
                  &abuf[b][(kl_ * GM) * 32]);                                 \
    }                                                                         \
  }

#define PIPE_WAIT(N) {                                                        \
    asm volatile("s_waitcnt vmcnt(" #N ") lgkmcnt(0)" ::: "memory");          \
    __builtin_amdgcn_sched_barrier(0);                                        \
    __builtin_amdgcn_s_barrier();                                             \
    __builtin_amdgcn_sched_barrier(0);                                        \
  }

#define PIPE_END {                                                            \
    __builtin_amdgcn_sched_barrier(0);                                        \
    __builtin_amdgcn_s_barrier();                                             \
    __builtin_amdgcn_sched_barrier(0);                                        \
  }

#define LOADA(b, kl)                                                          \
    const short8 a0 = *(const short8*)&abuf[b][((kl) * GM + nn) * 32 + q * 8];\
    const uint2 rv = rbuf[b][(kl) * GM + nn];                                 \
    U8 t1_; t1_.u = make_uint4(rv.x, rv.y, 0u, 0u);                           \
    const short8 a1 = t1_.s;

#define STAT(h, mx, s1, s2)                                                   \
    _Pragma("unroll")                                                         \
    for (int r = 0; r < 4; ++r) {                                             \
      float hv = (h)[r];                                                      \
      (mx)[r] = fmaxf((mx)[r], hv);                                           \
      (s1) += hv;                                                             \
      (s2) = fmaf(hv, hv, (s2));                                              \
    }

#define INIT_MX                                                               \
    _Pragma("unroll")                                                         \
    for (int r = 0; r < 4; ++r) {                                             \
      mx1[r] = -3.4e38f; mx2[r] = -3.4e38f; mx3[r] = -3.4e38f;                \
    }

  // half 0 of a group: kg 0-9 -> branches 1,2,3; kg 10-19 -> branches 2,3
#define COMPUTE_H0(b) {                                                       \
    _Pragma("unroll 2")                                                       \
    for (int kl = 0; kl < 10; ++kl) {                                         \
      LOADA(b, kl)                                                            \
      f32x4 h3 = __builtin_amdgcn_mfma_f32_16x16x32_bf16(a0, bw3[0], zz, 0, 0, 0); \
      h3 = __builtin_amdgcn_mfma_f32_16x16x32_bf16(a1, bw3[1], h3, 0, 0, 0);  \
      f32x4 h2 = __builtin_amdgcn_mfma_f32_16x16x32_bf16(a0, bw2[0], zz, 0, 0, 0); \
      h2 = __builtin_amdgcn_mfma_f32_16x16x32_bf16(a1, bw2[1], h2, 0, 0, 0);  \
      f32x4 h1 = __builtin_amdgcn_mfma_f32_16x16x32_bf16(a0, bw1[0], zz, 0, 0, 0); \
      h1 = __builtin_amdgcn_mfma_f32_16x16x32_bf16(a1, bw1[1], h1, 0, 0, 0);  \
      STAT(h3, mx3, s1b2, s2b2)                                               \
      STAT(h2, mx2, s1b1, s2b1)                                               \
      STAT(h1, mx1, s1b0, s2b0)                                               \
    }                                                                         \
    _Pragma("unroll 2")                                                       \
    for (int kl = 10; kl < 20; ++kl) {                                        \
      LOADA(b, kl)                                                            \
      f32x4 h3 = __builtin_amdgcn_mfma_f32_16x16x32_bf16(a0, bw3[0], zz, 0, 0, 0); \
      h3 = __builtin_amdgcn_mfma_f32_16x16x32_bf16(a1, bw3[1], h3, 0, 0, 0);  \
      f32x4 h2 = __builtin_amdgcn_mfma_f32_16x16x32_bf16(a0, bw2[0], zz, 0, 0, 0); \
      h2 = __builtin_amdgcn_mfma_f32_16x16x32_bf16(a1, bw2[1], h2, 0, 0, 0);  \
      STAT(h3, mx3, s1b2, s2b2)                                               \
      STAT(h2, mx2, s1b1, s2b1)                                               \
    }                                                                         \
  }

  // half 1 of a group: kg 20-39 -> branch 3 only
#define COMPUTE_H1(b) {                                                       \
    _Pragma("unroll 2")                                                       \
    for (int kl = 0; kl < 20; ++kl) {                                         \
      LOADA(b, kl)                                                            \
      f32x4 h3 = __builtin_amdgcn_mfma_f32_16x16x32_bf16(a0, bw3[0], zz, 0, 0, 0); \
      h3 = __builtin_amdgcn_mfma_f32_16x16x32_bf16(a1, bw3[1], h3, 0, 0, 0);  \
      STAT(h3, mx3, s1b2, s2b2)                                               \
    }                                                                         \
  }

#define WRITE_HMAX(baseV) {                                                   \
    _Pragma("unroll")                                                         \
    for (int r = 0; r < 4; ++r) {                                             \
      int m_ = (baseV) + q * 4 + r;                                           \
      hmax1[(size_t)m_ * CO + cg] = mx1[r];                                   \
      hmax2[(size_t)m_ * CO + cg] = mx2[r];                                   \
      hmax3[(size_t)m_ * CO + cg] = mx3[r];                                   \
    }                                                                         \
  }

  float mx1[4], mx2[4], mx3[4];

  // ---- prologue: stage half 0 into buf0 ----
  STAGE_REL(0, 0, 0, base0)
  STAGE_XB(0, 0, 0)

  // ---- t=0: stage (g0,h1)->buf1, compute (g0,h0) from buf0 ----
  STAGE_REL(0, 1, 1, base0)
  STAGE_XB(0, 1, 1)
  PIPE_WAIT(5)
  INIT_MX
  COMPUTE_H0(0)
  PIPE_END

  // ---- t=1: stage (g1,h0)->buf0, compute (g0,h1) from buf1 ----
  STAGE_REL(1, 0, 0, base1)
  STAGE_XB(1, 0, 0)
  PIPE_WAIT(5)
  COMPUTE_H1(1)
  WRITE_HMAX(base0)
  PIPE_END

  // ---- t=2: stage (g1,h1)->buf1, compute (g1,h0) from buf0 ----
  STAGE_REL(1, 1, 1, base1)
  STAGE_XB(1, 1, 1)
  PIPE_WAIT(5)
  INIT_MX
  COMPUTE_H0(0)
  PIPE_END

  // ---- t=3: drain, compute (g1,h1) from buf1 ----
  PIPE_WAIT(0)
  COMPUTE_H1(1)
  WRITE_HMAX(base1)

#undef STAGE_REL
#undef STAGE_XB
#undef LOADA
#undef STAT
#undef COMPUTE_H0
#undef COMPUTE_H1
#undef WRITE_HMAX

  // ---- stats: reduce across quads (same c), then one atomic per (c,stat) ----
  {
    float v;
    v = s1b0; v += __shfl_xor(v, 16); v += __shfl_xor(v, 32);
    if (q == 0) atomicAdd(&stats[0 * 64 + cg], v);
    v = s1b1; v += __shfl_xor(v, 16); v += __shfl_xor(v, 32);
    if (q == 0) atomicAdd(&stats[1 * 64 + cg], v);
    v = s1b2; v += __shfl_xor(v, 16); v += __shfl_xor(v, 32);
    if (q == 0) atomicAdd(&stats[2 * 64 + cg], v);
    v = s2b0; v += __shfl_xor(v, 16); v += __shfl_xor(v, 32);
    if (q == 0) atomicAdd(&stats[192 + 0 * 64 + cg], v);
    v = s2b1; v += __shfl_xor(v, 16); v += __shfl_xor(v, 32);
    if (q == 0) atomicAdd(&stats[192 + 1 * 64 + cg], v);
    v = s2b2; v += __shfl_xor(v, 16); v += __shfl_xor(v, 32);
    if (q == 0) atomicAdd(&stats[192 + 2 * 64 + cg], v);
  }
}

// ---------------------------------------------------------------------------
// k_fuse (proven form, one group per block): BN affines in preamble; ycat
// staged bf16 in LDS; z = ycat@w + b via 6 accumulating MFMAs; z stats.
// ---------------------------------------------------------------------------
__global__ void __launch_bounds__(256) k_fuse(
    const float* __restrict__ hmax1, const float* __restrict__ hmax2,
    const float* __restrict__ hmax3,
    const float* __restrict__ w, const float* __restrict__ bias,
    const float* __restrict__ g1, const float* __restrict__ g2,
    const float* __restrict__ g3,
    const float* __restrict__ be1, const float* __restrict__ be2,
    const float* __restrict__ be3,
    float* __restrict__ zout, float* __restrict__ stats, int M)
{
  __shared__ __align__(16) short ybuf[GM * FS];   // 6400 B
  __shared__ float sc_s[192], sh_s[192];

  const int tid  = threadIdx.x;
  const int wv   = tid >> 6;
  const int lane = tid & 63;
  const int q    = lane >> 4;
  const int nn   = lane & 15;
  const int cg   = wv * 16 + nn;

  if (tid < 192) {
    int b = tid >> 6, c = tid & 63;
    float cnt = (float)M * (float)(10 << b);
    float mu  = stats[tid] / cnt;
    float var = stats[192 + tid] / cnt - mu * mu;
    const float* g  = (b == 0) ? g1 : ((b == 1) ? g2 : g3);
    const float* be = (b == 0) ? be1 : ((b == 1) ? be2 : be3);
    float sc = g[c] * rsqrtf(var + BN_EPS);
    sc_s[tid] = sc;
    sh_s[tid] = be[c] - mu * sc;
  }

  short8 bw[6];
#pragma unroll
  for (int s = 0; s < 6; ++s)
#pragma unroll
    for (int j = 0; j < 8; ++j)
      bw[s][j] = f2bf(w[(s * 32 + q * 8 + j) * CO + cg]);

  const float bia = bias[cg];
  float s1 = 0.f, s2 = 0.f;

  const int ml_s = tid >> 4;          // staging: m_local 0..15
  const int c4   = (tid & 15) * 4;    // staging: 4 channels
  __syncthreads();                    // sc_s/sh_s ready

  const int base = blockIdx.x * GM;
  // ---- stage ycat (affine + relu + bf16) ----
#pragma unroll
  for (int b = 0; b < 3; ++b) {
    const float* hb = (b == 0) ? hmax1 : ((b == 1) ? hmax2 : hmax3);
    float4 v  = *(const float4*)&hb[(size_t)(base + ml_s) * CO + c4];
    float4 sc = *(const float4*)&sc_s[b * 64 + c4];
    float4 sh = *(const float4*)&sh_s[b * 64 + c4];
    float y0 = fmaxf(fmaf(v.x, sc.x, sh.x), 0.f);
    float y1 = fmaxf(fmaf(v.y, sc.y, sh.y), 0.f);
    float y2 = fmaxf(fmaf(v.z, sc.z, sh.z), 0.f);
    float y3 = fmaxf(fmaf(v.w, sc.w, sh.w), 0.f);
    *(uint2*)&ybuf[ml_s * FS + b * 64 + c4] = make_uint2(pk2(y0, y1), pk2(y2, y3));
  }
  __syncthreads();
  // ---- 6 accumulating MFMAs ----
  const short* ar = &ybuf[nn * FS + q * 8];
  f32x4 acc = {0.f, 0.f, 0.f, 0.f};
#pragma unroll
  for (int s = 0; s < 6; ++s) {
    short8 a = *(const short8*)(ar + s * 32);
    acc = __builtin_amdgcn_mfma_f32_16x16x32_bf16(a, bw[s], acc, 0, 0, 0);
  }
#pragma unroll
  for (int r = 0; r < 4; ++r) {
    float z = acc[r] + bia;
    int m = base + q * 4 + r;
    zout[(size_t)m * CO + cg] = z;
    s1 += z; s2 = fmaf(z, z, s2);
  }

  float v;
  v = s1; v += __shfl_xor(v, 16); v += __shfl_xor(v, 32);
  if (q == 0) atomicAdd(&stats[384 + cg], v);
  v = s2; v += __shfl_xor(v, 16); v += __shfl_xor(v, 32);
  if (q == 0) atomicAdd(&stats[448 + cg], v);
}

// ---------------------------------------------------------------------------
// k_out: final BN params inline; y = relu(BN(z)) in place, float4; n_o.
// ---------------------------------------------------------------------------
__global__ void k_out(float* __restrict__ y, const float* __restrict__ stats,
                      const float* __restrict__ g, const float* __restrict__ be,
                      float* __restrict__ out_no, int M)
{
  int t = blockIdx.x * blockDim.x + threadIdx.x;
  int total = M * 16;                 // in float4 units (M*64 floats)
  if (t < total) {
    int c0 = (t & 15) * 4;
    float rm = 1.f / (float)M;
    float4 v  = ((const float4*)y)[t];
    float4 sA = *(const float4*)&stats[384 + c0];
    float4 sB = *(const float4*)&stats[448 + c0];
    float4 gv = *(const float4*)&g[c0];
    float4 bv = *(const float4*)&be[c0];
    float mu0 = sA.x * rm, mu1 = sA.y * rm, mu2 = sA.z * rm, mu3 = sA.w * rm;
    float sc0 = gv.x * rsqrtf(sB.x * rm - mu0 * mu0 + BN_EPS);
    float sc1 = gv.y * rsqrtf(sB.y * rm - mu1 * mu1 + BN_EPS);
    float sc2 = gv.z * rsqrtf(sB.z * rm - mu2 * mu2 + BN_EPS);
    float sc3 = gv.w * rsqrtf(sB.w * rm - mu3 * mu3 + BN_EPS);
    float4 o;
    o.x = fmaxf(fmaf(v.x, sc0, bv.x - mu0 * sc0), 0.f);
    o.y = fmaxf(fmaf(v.y, sc1, bv.y - mu1 * sc1), 0.f);
    o.z = fmaxf(fmaf(v.z, sc2, bv.z - mu2 * sc2), 0.f);
    o.w = fmaxf(fmaf(v.w, sc3, bv.w - mu3 * sc3), 0.f);
    ((float4*)y)[t] = o;
  }
  if (t == 0) out_no[0] = (float)M;
}

extern "C" void kernel_launch(void* const* d_in, const int* in_sizes, int n_in,
                              void* d_out, int out_size, void* d_ws, size_t ws_size,
                              hipStream_t stream) {
  const float* p   = (const float*)d_in[0];
  const float* x   = (const float*)d_in[1];
  const int*   fps = (const int*)d_in[3];
  const int*   knn = (const int*)d_in[4];
  const float* w1  = (const float*)d_in[5];
  const float* w2  = (const float*)d_in[6];
  const float* w3  = (const float*)d_in[7];
  const float* w   = (const float*)d_in[8];
  const float* b   = (const float*)d_in[9];
  const float* g1  = (const float*)d_in[10];
  const float* g2  = (const float*)d_in[11];
  const float* g3  = (const float*)d_in[12];
  const float* g   = (const float*)d_in[13];
  const float* be1 = (const float*)d_in[14];
  const float* be2 = (const float*)d_in[15];
  const float* be3 = (const float*)d_in[16];
  const float* be  = (const float*)d_in[17];

  const int M = in_sizes[3];
  const int N = in_sizes[1] / 32;   // x is [N, 32]

  float* ws    = (float*)d_ws;
  float* hmax1 = ws;
  float* hmax2 = hmax1 + (size_t)M * 64;
  float* hmax3 = hmax2 + (size_t)M * 64;
  float* stats = hmax3 + (size_t)M * 64;   // 512 floats

  float* out    = (float*)d_out;
  float* out_np = out;                       // [0, 3M)
  float* out_y  = out + (size_t)3 * M;       // [3M, 67M)
  float* out_no = out + (size_t)67 * M;      // [67M]
  short* xb     = (short*)out_y;             // bf16 x table, dead before k_fuse

  int pre_threads = 4 * N + M + 512;
  k_pre<<<(pre_threads + 255) / 256, 256, 0, stream>>>(x, p, fps, xb, out_np,
                                                       stats, out_no, N, M);
  k_branch<<<M / (GM * 2), 256, 0, stream>>>(p, xb, out_np, knn, w1, w2, w3,
                                             hmax1, hmax2, hmax3, stats, M);
  k_fuse<<<M / GM, 256, 0, stream>>>(hmax1, hmax2, hmax3, w, b,
                                     g1, g2, g3, be1, be2, be3,
                                     out_y, stats, M);
  k_out<<<(M * 16 + 255) / 256, 256, 0, stream>>>(out_y, stats, g, be, out_no, M);
}

// Round 8
// 259.955 us; speedup vs baseline: 1.3419x; 1.2174x over previous
//
#include <hip/hip_runtime.h>
#include <hip/hip_bf16.h>

#define K3   40
#define CO   64
#define GM   16      // m per group (= MFMA tile rows)
#define CHK  20      // k-slots per staged half (2 halves per group)
#define FS   200     // shorts per ycat row in LDS (192 data + 8 pad)
#define BN_EPS 1e-5f

typedef __attribute__((ext_vector_type(8))) short short8;
typedef __attribute__((ext_vector_type(4))) float f32x4;

union U8 { short8 s; uint4 u; };

static __device__ __forceinline__ short f2bf(float f) {
  union { __hip_bfloat16 b; short s; } u; u.b = __float2bfloat16(f); return u.s;
}
static __device__ __forceinline__ unsigned pk2(float a, float b) {
  union { __hip_bfloat16 b; unsigned short s; } ua, ub;
  ua.b = __float2bfloat16(a); ub.b = __float2bfloat16(b);
  return (unsigned)ua.s | ((unsigned)ub.s << 16);
}
static __device__ __forceinline__ void gload_lds16(const void* g, void* l) {
  __builtin_amdgcn_global_load_lds(
      (const __attribute__((address_space(1))) unsigned int*)g,
      (__attribute__((address_space(3))) unsigned int*)l, 16, 0, 0);
}

// ---------------------------------------------------------------------------
// Output buffer is FLOAT32. Layout: n_p[M*3] | y[M*64] | n_o[1].
// xb (bf16 copy of x) lives in the out_y region during k_pre..k_branch;
// k_fuse overwrites it with z afterwards (stream-ordered).
// Workspace: hmax1|hmax2|hmax3 (3*M*64 f32) | stats(512 f32)
// ---------------------------------------------------------------------------

// k_pre: x -> bf16 table | n_p centroid table | stats zero | n_o.
__global__ void k_pre(const float* __restrict__ x, const float* __restrict__ p,
                      const int* __restrict__ fps,
                      short* __restrict__ xb, float* __restrict__ out_np,
                      float* __restrict__ stats, float* __restrict__ out_no,
                      int N, int M)
{
  int t = blockIdx.x * blockDim.x + threadIdx.x;
  int nxb = N * 4;                       // N*32 elems / 8 per thread
  if (t < nxb) {
    const float4* src = (const float4*)x + (size_t)t * 2;
    float4 f0 = src[0], f1 = src[1];
    uint4 o = make_uint4(pk2(f0.x, f0.y), pk2(f0.z, f0.w),
                         pk2(f1.x, f1.y), pk2(f1.z, f1.w));
    ((uint4*)xb)[t] = o;
    return;
  }
  int t2 = t - nxb;
  if (t2 < M) {
    int fi = fps[t2];
    out_np[(size_t)t2 * 3 + 0] = p[(size_t)fi * 3 + 0];
    out_np[(size_t)t2 * 3 + 1] = p[(size_t)fi * 3 + 1];
    out_np[(size_t)t2 * 3 + 2] = p[(size_t)fi * 3 + 2];
    return;
  }
  int t3 = t2 - M;
  if (t3 < 512) {
    stats[t3] = 0.f;
    if (t3 == 0) out_no[0] = (float)M;
  }
}

// ---------------------------------------------------------------------------
// k_branch (FROZEN, r7-proven 102 us): 2 groups per block, 4 pipelined halves
// of 20 k-slots. Double-buffered LDS staging: stage half t+1 (5 gload_lds per
// thread + rel from L2-resident p) -> s_waitcnt vmcnt(5) keeps the new DMAs
// in flight across a raw s_barrier -> compute half t. 51.2 KB LDS ->
// 3 blocks/CU: minimum-traffic operating point with intra-block overlap.
// ---------------------------------------------------------------------------
__global__ void __launch_bounds__(256, 3) k_branch(
    const float* __restrict__ p, const short* __restrict__ xb,
    const float* __restrict__ np, const int* __restrict__ knn,
    const float* __restrict__ w1, const float* __restrict__ w2,
    const float* __restrict__ w3,
    float* __restrict__ hmax1, float* __restrict__ hmax2,
    float* __restrict__ hmax3,
    float* __restrict__ stats, int M)
{
  __shared__ __align__(16) short abuf[2][CHK * GM * 32];   // 2 x 20480 B
  __shared__ __align__(16) uint2 rbuf[2][CHK * GM];        // 2 x 2560 B
  __shared__ __align__(16) int   knn_s[2][GM * K3];        // 2 x 2560 B

  const int tid  = threadIdx.x;
  const int wv   = tid >> 6;
  const int lane = tid & 63;
  const int q    = lane >> 4;    // quad
  const int nn   = lane & 15;    // A-row (m_local) and B-col within tile
  const int cg   = wv * 16 + nn; // this lane's output channel
  const int sub8 = (lane & 3) * 8;   // 16B sub-chunk of a 64B row (in shorts)
  const int rml  = lane >> 2;        // m_local of the staged row
  const int base0 = blockIdx.x * GM;
  const int base1 = (blockIdx.x + gridDim.x) * GM;

  // B fragments: lane holds w[k][cg] permuted to feat d-order:
  // d<32 -> w row 3+d (x part); d in [32,35) -> w row d-32 (rel); else 0.
  short8 bw1[2], bw2[2], bw3[2];
#pragma unroll
  for (int s = 0; s < 2; ++s) {
#pragma unroll
    for (int j = 0; j < 8; ++j) {
      int d = s * 32 + q * 8 + j;
      int row = (d < 32) ? (3 + d) : ((d < 35) ? (d - 32) : -1);
      bw1[s][j] = f2bf(row >= 0 ? w1[row * CO + cg] : 0.f);
      bw2[s][j] = f2bf(row >= 0 ? w2[row * CO + cg] : 0.f);
      bw3[s][j] = f2bf(row >= 0 ? w3[row * CO + cg] : 0.f);
    }
  }

  // stage knn for BOTH groups once (contiguous, int4-coalesced)
  if (tid < 160) {
    ((int4*)knn_s[0])[tid] = ((const int4*)(knn + (size_t)base0 * K3))[tid];
    ((int4*)knn_s[1])[tid] = ((const int4*)(knn + (size_t)base1 * K3))[tid];
  }
  __syncthreads();

  float s1b0 = 0.f, s1b1 = 0.f, s1b2 = 0.f;
  float s2b0 = 0.f, s2b1 = 0.f, s2b2 = 0.f;
  const f32x4 zz = {0.f, 0.f, 0.f, 0.f};

  // rel rows (320 per half): thread tid does rr=tid, tid<64 also rr=256+tid.
#define STAGE_REL(gI, half, b, baseV) {                                       \
    int ml_ = tid & 15;                                                       \
    const float* npp_ = np + (size_t)((baseV) + ml_) * 3;                     \
    float npx_ = npp_[0], npy_ = npp_[1], npz_ = npp_[2];                     \
    int kl0_ = tid >> 4;                                                      \
    int gi0_ = knn_s[gI][ml_ * K3 + (half) * CHK + kl0_];                     \
    const float* pg0_ = p + (size_t)gi0_ * 3;                                 \
    rbuf[b][kl0_ * GM + ml_] =                                                \
        make_uint2(pk2(pg0_[0] - npx_, pg0_[1] - npy_),                       \
                   pk2(pg0_[2] - npz_, 0.f));                                 \
    if (tid < 64) {                                                           \
      int kl1_ = 16 + (tid >> 4);                                             \
      int gi1_ = knn_s[gI][ml_ * K3 + (half) * CHK + kl1_];                   \
      const float* pg1_ = p + (size_t)gi1_ * 3;                               \
      rbuf[b][kl1_ * GM + ml_] =                                              \
          make_uint2(pk2(pg1_[0] - npx_, pg1_[1] - npy_),                     \
                     pk2(pg1_[2] - npz_, 0.f));                               \
    }                                                                         \
  }

  // 5 pure-DMA loads per thread; wave wv owns kl in [wv*5, wv*5+5)
#define STAGE_XB(gI, half, b) {                                               \
    _Pragma("unroll")                                                         \
    for (int j = 0; j < 5; ++j) {                                             \
      int kl_ = wv * 5 + j;                                                   \
      int gi_ = knn_s[gI][rml * K3 + (half) * CHK + kl_];                     \
      gload_lds16(xb + (size_t)gi_ * 32 + sub8,                               \
                  &abuf[b][(kl_ * GM) * 32]);                                 \
    }                                                                         \
  }

#define PIPE_WAIT(N) {                                                        \
    asm volatile("s_waitcnt vmcnt(" #N ") lgkmcnt(0)" ::: "memory");          \
    __builtin_amdgcn_sched_barrier(0);                                        \
    __builtin_amdgcn_s_barrier();                                             \
    __builtin_amdgcn_sched_barrier(0);                                        \
  }

#define PIPE_END {                                                            \
    __builtin_amdgcn_sched_barrier(0);                                        \
    __builtin_amdgcn_s_barrier();                                             \
    __builtin_amdgcn_sched_barrier(0);                                        \
  }

#define LOADA(b, kl)                                                          \
    const short8 a0 = *(const short8*)&abuf[b][((kl) * GM + nn) * 32 + q * 8];\
    const uint2 rv = rbuf[b][(kl) * GM + nn];                                 \
    U8 t1_; t1_.u = make_uint4(rv.x, rv.y, 0u, 0u);                           \
    const short8 a1 = t1_.s;

#define STAT(h, mx, s1, s2)                                                   \
    _Pragma("unroll")                                                         \
    for (int r = 0; r < 4; ++r) {                                             \
      float hv = (h)[r];                                                      \
      (mx)[r] = fmaxf((mx)[r], hv);                                           \
      (s1) += hv;                                                             \
      (s2) = fmaf(hv, hv, (s2));                                              \
    }

#define INIT_MX                                                               \
    _Pragma("unroll")                                                         \
    for (int r = 0; r < 4; ++r) {                                             \
      mx1[r] = -3.4e38f; mx2[r] = -3.4e38f; mx3[r] = -3.4e38f;                \
    }

  // half 0 of a group: kg 0-9 -> branches 1,2,3; kg 10-19 -> branches 2,3
#define COMPUTE_H0(b) {                                                       \
    _Pragma("unroll 2")                                                       \
    for (int kl = 0; kl < 10; ++kl) {                                         \
      LOADA(b, kl)                                                            \
      f32x4 h3 = __builtin_amdgcn_mfma_f32_16x16x32_bf16(a0, bw3[0], zz, 0, 0, 0); \
      h3 = __builtin_amdgcn_mfma_f32_16x16x32_bf16(a1, bw3[1], h3, 0, 0, 0);  \
      f32x4 h2 = __builtin_amdgcn_mfma_f32_16x16x32_bf16(a0, bw2[0], zz, 0, 0, 0); \
      h2 = __builtin_amdgcn_mfma_f32_16x16x32_bf16(a1, bw2[1], h2, 0, 0, 0);  \
      f32x4 h1 = __builtin_amdgcn_mfma_f32_16x16x32_bf16(a0, bw1[0], zz, 0, 0, 0); \
      h1 = __builtin_amdgcn_mfma_f32_16x16x32_bf16(a1, bw1[1], h1, 0, 0, 0);  \
      STAT(h3, mx3, s1b2, s2b2)                                               \
      STAT(h2, mx2, s1b1, s2b1)                                               \
      STAT(h1, mx1, s1b0, s2b0)                                               \
    }                                                                         \
    _Pragma("unroll 2")                                                       \
    for (int kl = 10; kl < 20; ++kl) {                                        \
      LOADA(b, kl)                                                            \
      f32x4 h3 = __builtin_amdgcn_mfma_f32_16x16x32_bf16(a0, bw3[0], zz, 0, 0, 0); \
      h3 = __builtin_amdgcn_mfma_f32_16x16x32_bf16(a1, bw3[1], h3, 0, 0, 0);  \
      f32x4 h2 = __builtin_amdgcn_mfma_f32_16x16x32_bf16(a0, bw2[0], zz, 0, 0, 0); \
      h2 = __builtin_amdgcn_mfma_f32_16x16x32_bf16(a1, bw2[1], h2, 0, 0, 0);  \
      STAT(h3, mx3, s1b2, s2b2)                                               \
      STAT(h2, mx2, s1b1, s2b1)                                               \
    }                                                                         \
  }

  // half 1 of a group: kg 20-39 -> branch 3 only
#define COMPUTE_H1(b) {                                                       \
    _Pragma("unroll 2")                                                       \
    for (int kl = 0; kl < 20; ++kl) {                                         \
      LOADA(b, kl)                                                            \
      f32x4 h3 = __builtin_amdgcn_mfma_f32_16x16x32_bf16(a0, bw3[0], zz, 0, 0, 0); \
      h3 = __builtin_amdgcn_mfma_f32_16x16x32_bf16(a1, bw3[1], h3, 0, 0, 0);  \
      STAT(h3, mx3, s1b2, s2b2)                                               \
    }                                                                         \
  }

#define WRITE_HMAX(baseV) {                                                   \
    _Pragma("unroll")                                                         \
    for (int r = 0; r < 4; ++r) {                                             \
      int m_ = (baseV) + q * 4 + r;                                           \
      hmax1[(size_t)m_ * CO + cg] = mx1[r];                                   \
      hmax2[(size_t)m_ * CO + cg] = mx2[r];                                   \
      hmax3[(size_t)m_ * CO + cg] = mx3[r];                                   \
    }                                                                         \
  }

  float mx1[4], mx2[4], mx3[4];

  // ---- prologue: stage half 0 into buf0 ----
  STAGE_REL(0, 0, 0, base0)
  STAGE_XB(0, 0, 0)

  // ---- t=0: stage (g0,h1)->buf1, compute (g0,h0) from buf0 ----
  STAGE_REL(0, 1, 1, base0)
  STAGE_XB(0, 1, 1)
  PIPE_WAIT(5)
  INIT_MX
  COMPUTE_H0(0)
  PIPE_END

  // ---- t=1: stage (g1,h0)->buf0, compute (g0,h1) from buf1 ----
  STAGE_REL(1, 0, 0, base1)
  STAGE_XB(1, 0, 0)
  PIPE_WAIT(5)
  COMPUTE_H1(1)
  WRITE_HMAX(base0)
  PIPE_END

  // ---- t=2: stage (g1,h1)->buf1, compute (g1,h0) from buf0 ----
  STAGE_REL(1, 1, 1, base1)
  STAGE_XB(1, 1, 1)
  PIPE_WAIT(5)
  INIT_MX
  COMPUTE_H0(0)
  PIPE_END

  // ---- t=3: drain, compute (g1,h1) from buf1 ----
  PIPE_WAIT(0)
  COMPUTE_H1(1)
  WRITE_HMAX(base1)

#undef STAGE_REL
#undef STAGE_XB
#undef LOADA
#undef STAT
#undef COMPUTE_H0
#undef COMPUTE_H1
#undef WRITE_HMAX

  // ---- stats: reduce across quads (same c), then one atomic per (c,stat) ----
  {
    float v;
    v = s1b0; v += __shfl_xor(v, 16); v += __shfl_xor(v, 32);
    if (q == 0) atomicAdd(&stats[0 * 64 + cg], v);
    v = s1b1; v += __shfl_xor(v, 16); v += __shfl_xor(v, 32);
    if (q == 0) atomicAdd(&stats[1 * 64 + cg], v);
    v = s1b2; v += __shfl_xor(v, 16); v += __shfl_xor(v, 32);
    if (q == 0) atomicAdd(&stats[2 * 64 + cg], v);
    v = s2b0; v += __shfl_xor(v, 16); v += __shfl_xor(v, 32);
    if (q == 0) atomicAdd(&stats[192 + 0 * 64 + cg], v);
    v = s2b1; v += __shfl_xor(v, 16); v += __shfl_xor(v, 32);
    if (q == 0) atomicAdd(&stats[192 + 1 * 64 + cg], v);
    v = s2b2; v += __shfl_xor(v, 16); v += __shfl_xor(v, 32);
    if (q == 0) atomicAdd(&stats[192 + 2 * 64 + cg], v);
  }
}

// ---------------------------------------------------------------------------
// k_fuse (r1-proven form, 1250 blocks x 3 groups): BN affines in preamble;
// ycat staged bf16 in LDS; z = ycat@w + b via 6 accumulating MFMAs; z stats.
// ---------------------------------------------------------------------------
__global__ void __launch_bounds__(256) k_fuse(
    const float* __restrict__ hmax1, const float* __restrict__ hmax2,
    const float* __restrict__ hmax3,
    const float* __restrict__ w, const float* __restrict__ bias,
    const float* __restrict__ g1, const float* __restrict__ g2,
    const float* __restrict__ g3,
    const float* __restrict__ be1, const float* __restrict__ be2,
    const float* __restrict__ be3,
    float* __restrict__ zout, float* __restrict__ stats, int M)
{
  __shared__ __align__(16) short ybuf[GM * FS];   // 6400 B
  __shared__ float sc_s[192], sh_s[192];

  const int tid  = threadIdx.x;
  const int wv   = tid >> 6;
  const int lane = tid & 63;
  const int q    = lane >> 4;
  const int nn   = lane & 15;
  const int cg   = wv * 16 + nn;

  if (tid < 192) {
    int b = tid >> 6, c = tid & 63;
    float cnt = (float)M * (float)(10 << b);
    float mu  = stats[tid] / cnt;
    float var = stats[192 + tid] / cnt - mu * mu;
    const float* g  = (b == 0) ? g1 : ((b == 1) ? g2 : g3);
    const float* be = (b == 0) ? be1 : ((b == 1) ? be2 : be3);
    float sc = g[c] * rsqrtf(var + BN_EPS);
    sc_s[tid] = sc;
    sh_s[tid] = be[c] - mu * sc;
  }

  short8 bw[6];
#pragma unroll
  for (int s = 0; s < 6; ++s)
#pragma unroll
    for (int j = 0; j < 8; ++j)
      bw[s][j] = f2bf(w[(s * 32 + q * 8 + j) * CO + cg]);

  const float bia = bias[cg];
  float s1 = 0.f, s2 = 0.f;

  const int ml_s = tid >> 4;          // staging: m_local 0..15
  const int c4   = (tid & 15) * 4;    // staging: 4 channels
  __syncthreads();                    // sc_s/sh_s ready

  const int ngrp = M / GM;
  for (int grp = blockIdx.x; grp < ngrp; grp += gridDim.x) {
    const int base = grp * GM;
    // ---- stage ycat (affine + relu + bf16) ----
#pragma unroll
    for (int b = 0; b < 3; ++b) {
      const float* hb = (b == 0) ? hmax1 : ((b == 1) ? hmax2 : hmax3);
      float4 v  = *(const float4*)&hb[(size_t)(base + ml_s) * CO + c4];
      float4 sc = *(const float4*)&sc_s[b * 64 + c4];
      float4 sh = *(const float4*)&sh_s[b * 64 + c4];
      float y0 = fmaxf(fmaf(v.x, sc.x, sh.x), 0.f);
      float y1 = fmaxf(fmaf(v.y, sc.y, sh.y), 0.f);
      float y2 = fmaxf(fmaf(v.z, sc.z, sh.z), 0.f);
      float y3 = fmaxf(fmaf(v.w, sc.w, sh.w), 0.f);
      *(uint2*)&ybuf[ml_s * FS + b * 64 + c4] = make_uint2(pk2(y0, y1), pk2(y2, y3));
    }
    __syncthreads();
    // ---- 6 accumulating MFMAs ----
    const short* ar = &ybuf[nn * FS + q * 8];
    f32x4 acc = {0.f, 0.f, 0.f, 0.f};
#pragma unroll
    for (int s = 0; s < 6; ++s) {
      short8 a = *(const short8*)(ar + s * 32);
      acc = __builtin_amdgcn_mfma_f32_16x16x32_bf16(a, bw[s], acc, 0, 0, 0);
    }
#pragma unroll
    for (int r = 0; r < 4; ++r) {
      float z = acc[r] + bia;
      int m = base + q * 4 + r;
      zout[(size_t)m * CO + cg] = z;
      s1 += z; s2 = fmaf(z, z, s2);
    }
    __syncthreads();   // ybuf reuse
  }

  float v;
  v = s1; v += __shfl_xor(v, 16); v += __shfl_xor(v, 32);
  if (q == 0) atomicAdd(&stats[384 + cg], v);
  v = s2; v += __shfl_xor(v, 16); v += __shfl_xor(v, 32);
  if (q == 0) atomicAdd(&stats[448 + cg], v);
}

// ---------------------------------------------------------------------------
// k_out: final BN params inline; y = relu(BN(z)) in place, float4; n_o.
// ---------------------------------------------------------------------------
__global__ void k_out(float* __restrict__ y, const float* __restrict__ stats,
                      const float* __restrict__ g, const float* __restrict__ be,
                      float* __restrict__ out_no, int M)
{
  int t = blockIdx.x * blockDim.x + threadIdx.x;
  int total = M * 16;                 // in float4 units (M*64 floats)
  if (t < total) {
    int c0 = (t & 15) * 4;
    float rm = 1.f / (float)M;
    float4 v  = ((const float4*)y)[t];
    float4 sA = *(const float4*)&stats[384 + c0];
    float4 sB = *(const float4*)&stats[448 + c0];
    float4 gv = *(const float4*)&g[c0];
    float4 bv = *(const float4*)&be[c0];
    float mu0 = sA.x * rm, mu1 = sA.y * rm, mu2 = sA.z * rm, mu3 = sA.w * rm;
    float sc0 = gv.x * rsqrtf(sB.x * rm - mu0 * mu0 + BN_EPS);
    float sc1 = gv.y * rsqrtf(sB.y * rm - mu1 * mu1 + BN_EPS);
    float sc2 = gv.z * rsqrtf(sB.z * rm - mu2 * mu2 + BN_EPS);
    float sc3 = gv.w * rsqrtf(sB.w * rm - mu3 * mu3 + BN_EPS);
    float4 o;
    o.x = fmaxf(fmaf(v.x, sc0, bv.x - mu0 * sc0), 0.f);
    o.y = fmaxf(fmaf(v.y, sc1, bv.y - mu1 * sc1), 0.f);
    o.z = fmaxf(fmaf(v.z, sc2, bv.z - mu2 * sc2), 0.f);
    o.w = fmaxf(fmaf(v.w, sc3, bv.w - mu3 * sc3), 0.f);
    ((float4*)y)[t] = o;
  }
  if (t == 0) out_no[0] = (float)M;
}

extern "C" void kernel_launch(void* const* d_in, const int* in_sizes, int n_in,
                              void* d_out, int out_size, void* d_ws, size_t ws_size,
                              hipStream_t stream) {
  const float* p   = (const float*)d_in[0];
  const float* x   = (const float*)d_in[1];
  const int*   fps = (const int*)d_in[3];
  const int*   knn = (const int*)d_in[4];
  const float* w1  = (const float*)d_in[5];
  const float* w2  = (const float*)d_in[6];
  const float* w3  = (const float*)d_in[7];
  const float* w   = (const float*)d_in[8];
  const float* b   = (const float*)d_in[9];
  const float* g1  = (const float*)d_in[10];
  const float* g2  = (const float*)d_in[11];
  const float* g3  = (const float*)d_in[12];
  const float* g   = (const float*)d_in[13];
  const float* be1 = (const float*)d_in[14];
  const float* be2 = (const float*)d_in[15];
  const float* be3 = (const float*)d_in[16];
  const float* be  = (const float*)d_in[17];

  const int M = in_sizes[3];
  const int N = in_sizes[1] / 32;   // x is [N, 32]

  float* ws    = (float*)d_ws;
  float* hmax1 = ws;
  float* hmax2 = hmax1 + (size_t)M * 64;
  float* hmax3 = hmax2 + (size_t)M * 64;
  float* stats = hmax3 + (size_t)M * 64;   // 512 floats

  float* out    = (float*)d_out;
  float* out_np = out;                       // [0, 3M)
  float* out_y  = out + (size_t)3 * M;       // [3M, 67M)
  float* out_no = out + (size_t)67 * M;      // [67M]
  short* xb     = (short*)out_y;             // bf16 x table, dead before k_fuse

  int pre_threads = 4 * N + M + 512;
  k_pre<<<(pre_threads + 255) / 256, 256, 0, stream>>>(x, p, fps, xb, out_np,
                                                       stats, out_no, N, M);
  k_branch<<<M / (GM * 2), 256, 0, stream>>>(p, xb, out_np, knn, w1, w2, w3,
                                             hmax1, hmax2, hmax3, stats, M);
  k_fuse<<<1250, 256, 0, stream>>>(hmax1, hmax2, hmax3, w, b,
                                   g1, g2, g3, be1, be2, be3,
                                   out_y, stats, M);
  k_out<<<(M * 16 + 255) / 256, 256, 0, stream>>>(out_y, stats, g, be, out_no, M);
}

// Round 9
// 239.916 us; speedup vs baseline: 1.4540x; 1.0835x over previous
//
#include <hip/hip_runtime.h>
#include <hip/hip_bf16.h>

#define K3   40
#define CO   64
#define GM   16      // m per group (= MFMA tile rows)
#define CHK  20      // k-slots per staged half (2 halves per group)
#define FS   200     // shorts per ycat row in LDS (192 data + 8 pad)
#define BN_EPS 1e-5f

typedef __attribute__((ext_vector_type(8))) short short8;
typedef __attribute__((ext_vector_type(4))) float f32x4;

union U8 { short8 s; uint4 u; };

static __device__ __forceinline__ short f2bf(float f) {
  union { __hip_bfloat16 b; short s; } u; u.b = __float2bfloat16(f); return u.s;
}
static __device__ __forceinline__ unsigned pk2(float a, float b) {
  union { __hip_bfloat16 b; unsigned short s; } ua, ub;
  ua.b = __float2bfloat16(a); ub.b = __float2bfloat16(b);
  return (unsigned)ua.s | ((unsigned)ub.s << 16);
}
static __device__ __forceinline__ void gload_lds16(const void* g, void* l) {
  __builtin_amdgcn_global_load_lds(
      (const __attribute__((address_space(1))) unsigned int*)g,
      (__attribute__((address_space(3))) unsigned int*)l, 16, 0, 0);
}

// ---------------------------------------------------------------------------
// Output buffer is FLOAT32. Layout: n_p[M*3] | y[M*64] | n_o[1].
// xb (bf16 copy of x) lives in the out_y region during k_pre..k_branch;
// k_fuse overwrites it with z afterwards (stream-ordered).
// Workspace: hmax1|hmax2|hmax3 (3*M*64 f32) | stats(512 f32)
// ---------------------------------------------------------------------------

// k_pre: x -> bf16 table | n_p centroid table | stats zero | n_o.
__global__ void k_pre(const float* __restrict__ x, const float* __restrict__ p,
                      const int* __restrict__ fps,
                      short* __restrict__ xb, float* __restrict__ out_np,
                      float* __restrict__ stats, float* __restrict__ out_no,
                      int N, int M)
{
  int t = blockIdx.x * blockDim.x + threadIdx.x;
  int nxb = N * 4;                       // N*32 elems / 8 per thread
  if (t < nxb) {
    const float4* src = (const float4*)x + (size_t)t * 2;
    float4 f0 = src[0], f1 = src[1];
    uint4 o = make_uint4(pk2(f0.x, f0.y), pk2(f0.z, f0.w),
                         pk2(f1.x, f1.y), pk2(f1.z, f1.w));
    ((uint4*)xb)[t] = o;
    return;
  }
  int t2 = t - nxb;
  if (t2 < M) {
    int fi = fps[t2];
    out_np[(size_t)t2 * 3 + 0] = p[(size_t)fi * 3 + 0];
    out_np[(size_t)t2 * 3 + 1] = p[(size_t)fi * 3 + 1];
    out_np[(size_t)t2 * 3 + 2] = p[(size_t)fi * 3 + 2];
    return;
  }
  int t3 = t2 - M;
  if (t3 < 512) {
    stats[t3] = 0.f;
    if (t3 == 0) out_no[0] = (float)M;
  }
}

// ---------------------------------------------------------------------------
// k_branch (FROZEN, r7/r8-proven 102 us): 2 groups per block, 4 pipelined
// halves of 20 k-slots. Double-buffered LDS staging with counted vmcnt(5)
// across raw s_barrier; 51.2 KB LDS -> 3 blocks/CU (minimum-traffic point).
// ---------------------------------------------------------------------------
__global__ void __launch_bounds__(256, 3) k_branch(
    const float* __restrict__ p, const short* __restrict__ xb,
    const float* __restrict__ np, const int* __restrict__ knn,
    const float* __restrict__ w1, const float* __restrict__ w2,
    const float* __restrict__ w3,
    float* __restrict__ hmax1, float* __restrict__ hmax2,
    float* __restrict__ hmax3,
    float* __restrict__ stats, int M)
{
  __shared__ __align__(16) short abuf[2][CHK * GM * 32];   // 2 x 20480 B
  __shared__ __align__(16) uint2 rbuf[2][CHK * GM];        // 2 x 2560 B
  __shared__ __align__(16) int   knn_s[2][GM * K3];        // 2 x 2560 B

  const int tid  = threadIdx.x;
  const int wv   = tid >> 6;
  const int lane = tid & 63;
  const int q    = lane >> 4;    // quad
  const int nn   = lane & 15;    // A-row (m_local) and B-col within tile
  const int cg   = wv * 16 + nn; // this lane's output channel
  const int sub8 = (lane & 3) * 8;   // 16B sub-chunk of a 64B row (in shorts)
  const int rml  = lane >> 2;        // m_local of the staged row
  const int base0 = blockIdx.x * GM;
  const int base1 = (blockIdx.x + gridDim.x) * GM;

  // B fragments: lane holds w[k][cg] permuted to feat d-order:
  // d<32 -> w row 3+d (x part); d in [32,35) -> w row d-32 (rel); else 0.
  short8 bw1[2], bw2[2], bw3[2];
#pragma unroll
  for (int s = 0; s < 2; ++s) {
#pragma unroll
    for (int j = 0; j < 8; ++j) {
      int d = s * 32 + q * 8 + j;
      int row = (d < 32) ? (3 + d) : ((d < 35) ? (d - 32) : -1);
      bw1[s][j] = f2bf(row >= 0 ? w1[row * CO + cg] : 0.f);
      bw2[s][j] = f2bf(row >= 0 ? w2[row * CO + cg] : 0.f);
      bw3[s][j] = f2bf(row >= 0 ? w3[row * CO + cg] : 0.f);
    }
  }

  // stage knn for BOTH groups once (contiguous, int4-coalesced)
  if (tid < 160) {
    ((int4*)knn_s[0])[tid] = ((const int4*)(knn + (size_t)base0 * K3))[tid];
    ((int4*)knn_s[1])[tid] = ((const int4*)(knn + (size_t)base1 * K3))[tid];
  }
  __syncthreads();

  float s1b0 = 0.f, s1b1 = 0.f, s1b2 = 0.f;
  float s2b0 = 0.f, s2b1 = 0.f, s2b2 = 0.f;
  const f32x4 zz = {0.f, 0.f, 0.f, 0.f};

  // rel rows (320 per half): thread tid does rr=tid, tid<64 also rr=256+tid.
#define STAGE_REL(gI, half, b, baseV) {                                       \
    int ml_ = tid & 15;                                                       \
    const float* npp_ = np + (size_t)((baseV) + ml_) * 3;                     \
    float npx_ = npp_[0], npy_ = npp_[1], npz_ = npp_[2];                     \
    int kl0_ = tid >> 4;                                                      \
    int gi0_ = knn_s[gI][ml_ * K3 + (half) * CHK + kl0_];                     \
    const float* pg0_ = p + (size_t)gi0_ * 3;                                 \
    rbuf[b][kl0_ * GM + ml_] =                                                \
        make_uint2(pk2(pg0_[0] - npx_, pg0_[1] - npy_),                       \
                   pk2(pg0_[2] - npz_, 0.f));                                 \
    if (tid < 64) {                                                           \
      int kl1_ = 16 + (tid >> 4);                                             \
      int gi1_ = knn_s[gI][ml_ * K3 + (half) * CHK + kl1_];                   \
      const float* pg1_ = p + (size_t)gi1_ * 3;                               \
      rbuf[b][kl1_ * GM + ml_] =                                              \
          make_uint2(pk2(pg1_[0] - npx_, pg1_[1] - npy_),                     \
                     pk2(pg1_[2] - npz_, 0.f));                               \
    }                                                                         \
  }

  // 5 pure-DMA loads per thread; wave wv owns kl in [wv*5, wv*5+5)
#define STAGE_XB(gI, half, b) {                                               \
    _Pragma("unroll")                                                         \
    for (int j = 0; j < 5; ++j) {                                             \
      int kl_ = wv * 5 + j;                                                   \
      int gi_ = knn_s[gI][rml * K3 + (half) * CHK + kl_];                     \
      gload_lds16(xb + (size_t)gi_ * 32 + sub8,                               \
                  &abuf[b][(kl_ * GM) * 32]);                                 \
    }                                                                         \
  }

#define PIPE_WAIT(N) {                                                        \
    asm volatile("s_waitcnt vmcnt(" #N ") lgkmcnt(0)" ::: "memory");          \
    __builtin_amdgcn_sched_barrier(0);                                        \
    __builtin_amdgcn_s_barrier();                                             \
    __builtin_amdgcn_sched_barrier(0);                                        \
  }

#define PIPE_END {                                                            \
    __builtin_amdgcn_sched_barrier(0);                                        \
    __builtin_amdgcn_s_barrier();                                             \
    __builtin_amdgcn_sched_barrier(0);                                        \
  }

#define LOADA(b, kl)                                                          \
    const short8 a0 = *(const short8*)&abuf[b][((kl) * GM + nn) * 32 + q * 8];\
    const uint2 rv = rbuf[b][(kl) * GM + nn];                                 \
    U8 t1_; t1_.u = make_uint4(rv.x, rv.y, 0u, 0u);                           \
    const short8 a1 = t1_.s;

#define STAT(h, mx, s1, s2)                                                   \
    _Pragma("unroll")                                                         \
    for (int r = 0; r < 4; ++r) {                                             \
      float hv = (h)[r];                                                      \
      (mx)[r] = fmaxf((mx)[r], hv);                                           \
      (s1) += hv;                                                             \
      (s2) = fmaf(hv, hv, (s2));                                              \
    }

#define INIT_MX                                                               \
    _Pragma("unroll")                                                         \
    for (int r = 0; r < 4; ++r) {                                             \
      mx1[r] = -3.4e38f; mx2[r] = -3.4e38f; mx3[r] = -3.4e38f;                \
    }

  // half 0 of a group: kg 0-9 -> branches 1,2,3; kg 10-19 -> branches 2,3
#define COMPUTE_H0(b) {                                                       \
    _Pragma("unroll 2")                                                       \
    for (int kl = 0; kl < 10; ++kl) {                                         \
      LOADA(b, kl)                                                            \
      f32x4 h3 = __builtin_amdgcn_mfma_f32_16x16x32_bf16(a0, bw3[0], zz, 0, 0, 0); \
      h3 = __builtin_amdgcn_mfma_f32_16x16x32_bf16(a1, bw3[1], h3, 0, 0, 0);  \
      f32x4 h2 = __builtin_amdgcn_mfma_f32_16x16x32_bf16(a0, bw2[0], zz, 0, 0, 0); \
      h2 = __builtin_amdgcn_mfma_f32_16x16x32_bf16(a1, bw2[1], h2, 0, 0, 0);  \
      f32x4 h1 = __builtin_amdgcn_mfma_f32_16x16x32_bf16(a0, bw1[0], zz, 0, 0, 0); \
      h1 = __builtin_amdgcn_mfma_f32_16x16x32_bf16(a1, bw1[1], h1, 0, 0, 0);  \
      STAT(h3, mx3, s1b2, s2b2)                                               \
      STAT(h2, mx2, s1b1, s2b1)                                               \
      STAT(h1, mx1, s1b0, s2b0)                                               \
    }                                                                         \
    _Pragma("unroll 2")                                                       \
    for (int kl = 10; kl < 20; ++kl) {                                        \
      LOADA(b, kl)                                                            \
      f32x4 h3 = __builtin_amdgcn_mfma_f32_16x16x32_bf16(a0, bw3[0], zz, 0, 0, 0); \
      h3 = __builtin_amdgcn_mfma_f32_16x16x32_bf16(a1, bw3[1], h3, 0, 0, 0);  \
      f32x4 h2 = __builtin_amdgcn_mfma_f32_16x16x32_bf16(a0, bw2[0], zz, 0, 0, 0); \
      h2 = __builtin_amdgcn_mfma_f32_16x16x32_bf16(a1, bw2[1], h2, 0, 0, 0);  \
      STAT(h3, mx3, s1b2, s2b2)                                               \
      STAT(h2, mx2, s1b1, s2b1)                                               \
    }                                                                         \
  }

  // half 1 of a group: kg 20-39 -> branch 3 only
#define COMPUTE_H1(b) {                                                       \
    _Pragma("unroll 2")                                                       \
    for (int kl = 0; kl < 20; ++kl) {                                         \
      LOADA(b, kl)                                                            \
      f32x4 h3 = __builtin_amdgcn_mfma_f32_16x16x32_bf16(a0, bw3[0], zz, 0, 0, 0); \
      h3 = __builtin_amdgcn_mfma_f32_16x16x32_bf16(a1, bw3[1], h3, 0, 0, 0);  \
      STAT(h3, mx3, s1b2, s2b2)                                               \
    }                                                                         \
  }

#define WRITE_HMAX(baseV) {                                                   \
    _Pragma("unroll")                                                         \
    for (int r = 0; r < 4; ++r) {                                             \
      int m_ = (baseV) + q * 4 + r;                                           \
      hmax1[(size_t)m_ * CO + cg] = mx1[r];                                   \
      hmax2[(size_t)m_ * CO + cg] = mx2[r];                                   \
      hmax3[(size_t)m_ * CO + cg] = mx3[r];                                   \
    }                                                                         \
  }

  float mx1[4], mx2[4], mx3[4];

  // ---- prologue: stage half 0 into buf0 ----
  STAGE_REL(0, 0, 0, base0)
  STAGE_XB(0, 0, 0)

  // ---- t=0: stage (g0,h1)->buf1, compute (g0,h0) from buf0 ----
  STAGE_REL(0, 1, 1, base0)
  STAGE_XB(0, 1, 1)
  PIPE_WAIT(5)
  INIT_MX
  COMPUTE_H0(0)
  PIPE_END

  // ---- t=1: stage (g1,h0)->buf0, compute (g0,h1) from buf1 ----
  STAGE_REL(1, 0, 0, base1)
  STAGE_XB(1, 0, 0)
  PIPE_WAIT(5)
  COMPUTE_H1(1)
  WRITE_HMAX(base0)
  PIPE_END

  // ---- t=2: stage (g1,h1)->buf1, compute (g1,h0) from buf0 ----
  STAGE_REL(1, 1, 1, base1)
  STAGE_XB(1, 1, 1)
  PIPE_WAIT(5)
  INIT_MX
  COMPUTE_H0(0)
  PIPE_END

  // ---- t=3: drain, compute (g1,h1) from buf1 ----
  PIPE_WAIT(0)
  COMPUTE_H1(1)
  WRITE_HMAX(base1)

#undef STAGE_REL
#undef STAGE_XB
#undef LOADA
#undef STAT
#undef COMPUTE_H0
#undef COMPUTE_H1
#undef WRITE_HMAX

  // ---- stats: reduce across quads (same c), then one atomic per (c,stat) ----
  {
    float v;
    v = s1b0; v += __shfl_xor(v, 16); v += __shfl_xor(v, 32);
    if (q == 0) atomicAdd(&stats[0 * 64 + cg], v);
    v = s1b1; v += __shfl_xor(v, 16); v += __shfl_xor(v, 32);
    if (q == 0) atomicAdd(&stats[1 * 64 + cg], v);
    v = s1b2; v += __shfl_xor(v, 16); v += __shfl_xor(v, 32);
    if (q == 0) atomicAdd(&stats[2 * 64 + cg], v);
    v = s2b0; v += __shfl_xor(v, 16); v += __shfl_xor(v, 32);
    if (q == 0) atomicAdd(&stats[192 + 0 * 64 + cg], v);
    v = s2b1; v += __shfl_xor(v, 16); v += __shfl_xor(v, 32);
    if (q == 0) atomicAdd(&stats[192 + 1 * 64 + cg], v);
    v = s2b2; v += __shfl_xor(v, 16); v += __shfl_xor(v, 32);
    if (q == 0) atomicAdd(&stats[192 + 2 * 64 + cg], v);
  }
}

// ---------------------------------------------------------------------------
// k_fuse v3: 469 blocks x 4 INDEPENDENT waves (no per-group barriers).
// Preamble (once per block): w staged via coalesced float4 -> bf16 LDS
// (pad-68 stride), BN affines -> LDS, one __syncthreads. Then each wave
// owns a private ybuf slice: stage ycat (affine+relu+bf16), wave-local
// lgkmcnt(0), 6 accumulating MFMAs, z write + stats. <=2 groups per wave.
// ---------------------------------------------------------------------------
__global__ void __launch_bounds__(256) k_fuse(
    const float* __restrict__ hmax1, const float* __restrict__ hmax2,
    const float* __restrict__ hmax3,
    const float* __restrict__ w, const float* __restrict__ bias,
    const float* __restrict__ g1, const float* __restrict__ g2,
    const float* __restrict__ g3,
    const float* __restrict__ be1, const float* __restrict__ be2,
    const float* __restrict__ be3,
    float* __restrict__ zout, float* __restrict__ stats, int M)
{
  __shared__ __align__(16) short wb[192 * 68];       // 26112 B (pad-68)
  __shared__ __align__(16) short ybuf[4][GM * FS];   // 25600 B (per-wave slice)
  __shared__ float sc_s[192], sh_s[192];

  const int tid  = threadIdx.x;
  const int wv   = tid >> 6;
  const int lane = tid & 63;
  const int q    = lane >> 4;
  const int nn   = lane & 15;
  const int cg   = wv * 16 + nn;

  // ---- preamble: w -> LDS bf16 (coalesced float4 reads) ----
#pragma unroll
  for (int u = 0; u < 12; ++u) {
    int ft = tid + u * 256;          // float4 id 0..3071
    int d  = ft >> 4;                // w row 0..191
    int c  = (ft & 15) * 4;
    float4 v = ((const float4*)w)[ft];
    *(uint2*)&wb[d * 68 + c] = make_uint2(pk2(v.x, v.y), pk2(v.z, v.w));
  }
  if (tid < 192) {
    int b = tid >> 6, c = tid & 63;
    float cnt = (float)M * (float)(10 << b);
    float mu  = stats[tid] / cnt;
    float var = stats[192 + tid] / cnt - mu * mu;
    const float* g  = (b == 0) ? g1 : ((b == 1) ? g2 : g3);
    const float* be = (b == 0) ? be1 : ((b == 1) ? be2 : be3);
    float sc = g[c] * rsqrtf(var + BN_EPS);
    sc_s[tid] = sc;
    sh_s[tid] = be[c] - mu * sc;
  }
  __syncthreads();   // wb + sc_s/sh_s ready; the only barrier in this kernel

  short8 bw[6];
#pragma unroll
  for (int s = 0; s < 6; ++s)
#pragma unroll
    for (int j = 0; j < 8; ++j)
      bw[s][j] = wb[(s * 32 + q * 8 + j) * 68 + cg];

  const float bia = bias[cg];
  float s1 = 0.f, s2 = 0.f;

  const int st_row = lane >> 2;        // staging: row 0..15 (4 lanes/row)
  const int st_c   = (lane & 3) * 16;  // staging: 16 channels per lane
  short* yb = &ybuf[wv][0];

  const int ngrp = M / GM;
  for (int grp = blockIdx.x * 4 + wv; grp < ngrp; grp += gridDim.x * 4) {
    const int base = grp * GM;
    // ---- stage ycat (affine + relu + bf16) into this wave's slice ----
#pragma unroll
    for (int b = 0; b < 3; ++b) {
      const float* hb = (b == 0) ? hmax1 : ((b == 1) ? hmax2 : hmax3);
      const float* src = hb + (size_t)(base + st_row) * CO + st_c;
#pragma unroll
      for (int u = 0; u < 4; ++u) {
        float4 v = *(const float4*)(src + u * 4);
        const float* scp = &sc_s[b * 64 + st_c + u * 4];
        const float* shp = &sh_s[b * 64 + st_c + u * 4];
        float y0 = fmaxf(fmaf(v.x, scp[0], shp[0]), 0.f);
        float y1 = fmaxf(fmaf(v.y, scp[1], shp[1]), 0.f);
        float y2 = fmaxf(fmaf(v.z, scp[2], shp[2]), 0.f);
        float y3 = fmaxf(fmaf(v.w, scp[3], shp[3]), 0.f);
        *(uint2*)&yb[st_row * FS + b * 64 + st_c + u * 4] =
            make_uint2(pk2(y0, y1), pk2(y2, y3));
      }
    }
    asm volatile("s_waitcnt lgkmcnt(0)" ::: "memory");   // wave-local drain
    __builtin_amdgcn_sched_barrier(0);
    // ---- 6 accumulating MFMAs ----
    const short* ar = yb + nn * FS + q * 8;
    f32x4 acc = {0.f, 0.f, 0.f, 0.f};
#pragma unroll
    for (int s = 0; s < 6; ++s) {
      short8 a = *(const short8*)(ar + s * 32);
      acc = __builtin_amdgcn_mfma_f32_16x16x32_bf16(a, bw[s], acc, 0, 0, 0);
    }
#pragma unroll
    for (int r = 0; r < 4; ++r) {
      float z = acc[r] + bia;
      int m = base + q * 4 + r;
      zout[(size_t)m * CO + cg] = z;
      s1 += z; s2 = fmaf(z, z, s2);
    }
  }

  float v;
  v = s1; v += __shfl_xor(v, 16); v += __shfl_xor(v, 32);
  if (q == 0) atomicAdd(&stats[384 + cg], v);
  v = s2; v += __shfl_xor(v, 16); v += __shfl_xor(v, 32);
  if (q == 0) atomicAdd(&stats[448 + cg], v);
}

// ---------------------------------------------------------------------------
// k_out: final BN params inline; y = relu(BN(z)) in place, float4; n_o.
// ---------------------------------------------------------------------------
__global__ void k_out(float* __restrict__ y, const float* __restrict__ stats,
                      const float* __restrict__ g, const float* __restrict__ be,
                      float* __restrict__ out_no, int M)
{
  int t = blockIdx.x * blockDim.x + threadIdx.x;
  int total = M * 16;                 // in float4 units (M*64 floats)
  if (t < total) {
    int c0 = (t & 15) * 4;
    float rm = 1.f / (float)M;
    float4 v  = ((const float4*)y)[t];
    float4 sA = *(const float4*)&stats[384 + c0];
    float4 sB = *(const float4*)&stats[448 + c0];
    float4 gv = *(const float4*)&g[c0];
    float4 bv = *(const float4*)&be[c0];
    float mu0 = sA.x * rm, mu1 = sA.y * rm, mu2 = sA.z * rm, mu3 = sA.w * rm;
    float sc0 = gv.x * rsqrtf(sB.x * rm - mu0 * mu0 + BN_EPS);
    float sc1 = gv.y * rsqrtf(sB.y * rm - mu1 * mu1 + BN_EPS);
    float sc2 = gv.z * rsqrtf(sB.z * rm - mu2 * mu2 + BN_EPS);
    float sc3 = gv.w * rsqrtf(sB.w * rm - mu3 * mu3 + BN_EPS);
    float4 o;
    o.x = fmaxf(fmaf(v.x, sc0, bv.x - mu0 * sc0), 0.f);
    o.y = fmaxf(fmaf(v.y, sc1, bv.y - mu1 * sc1), 0.f);
    o.z = fmaxf(fmaf(v.z, sc2, bv.z - mu2 * sc2), 0.f);
    o.w = fmaxf(fmaf(v.w, sc3, bv.w - mu3 * sc3), 0.f);
    ((float4*)y)[t] = o;
  }
  if (t == 0) out_no[0] = (float)M;
}

extern "C" void kernel_launch(void* const* d_in, const int* in_sizes, int n_in,
                              void* d_out, int out_size, void* d_ws, size_t ws_size,
                              hipStream_t stream) {
  const float* p   = (const float*)d_in[0];
  const float* x   = (const float*)d_in[1];
  const int*   fps = (const int*)d_in[3];
  const int*   knn = (const int*)d_in[4];
  const float* w1  = (const float*)d_in[5];
  const float* w2  = (const float*)d_in[6];
  const float* w3  = (const float*)d_in[7];
  const float* w   = (const float*)d_in[8];
  const float* b   = (const float*)d_in[9];
  const float* g1  = (const float*)d_in[10];
  const float* g2  = (const float*)d_in[11];
  const float* g3  = (const float*)d_in[12];
  const float* g   = (const float*)d_in[13];
  const float* be1 = (const float*)d_in[14];
  const float* be2 = (const float*)d_in[15];
  const float* be3 = (const float*)d_in[16];
  const float* be  = (const float*)d_in[17];

  const int M = in_sizes[3];
  const int N = in_sizes[1] / 32;   // x is [N, 32]

  float* ws    = (float*)d_ws;
  float* hmax1 = ws;
  float* hmax2 = hmax1 + (size_t)M * 64;
  float* hmax3 = hmax2 + (size_t)M * 64;
  float* stats = hmax3 + (size_t)M * 64;   // 512 floats

  float* out    = (float*)d_out;
  float* out_np = out;                       // [0, 3M)
  float* out_y  = out + (size_t)3 * M;       // [3M, 67M)
  float* out_no = out + (size_t)67 * M;      // [67M]
  short* xb     = (short*)out_y;             // bf16 x table, dead before k_fuse

  int pre_threads = 4 * N + M + 512;
  k_pre<<<(pre_threads + 255) / 256, 256, 0, stream>>>(x, p, fps, xb, out_np,
                                                       stats, out_no, N, M);
  k_branch<<<M / (GM * 2), 256, 0, stream>>>(p, xb, out_np, knn, w1, w2, w3,
                                             hmax1, hmax2, hmax3, stats, M);
  k_fuse<<<469, 256, 0, stream>>>(hmax1, hmax2, hmax3, w, b,
                                  g1, g2, g3, be1, be2, be3,
                                  out_y, stats, M);
  k_out<<<(M * 16 + 255) / 256, 256, 0, stream>>>(out_y, stats, g, be, out_no, M);
}